// Round 10
// baseline (152.791 us; speedup 1.0000x reference)
//
#include <hip/hip_runtime.h>

// ImplicitModelLoRA: X = relu(s*L*(R^T X) + B U^T) iterated; out = (C X + D U^T)^T
// Round-9 (resubmit; round-9 bench lost to GPU acquisition timeout):
// r7 structure (best so far) + f16 C/D epilogue (halves the 384 MB
// L2 epilogue traffic) + single full-K BUt (no partials) + zero atomics.
// k_prep (285 blocks): [0,256) BUt 32x32-tile GEMM; [256,284) pack L/R/C/D to
// f16; 284 computes proj norms -> s (plain store). k_main (256 blocks x 1024):
// R f16 in 32 VGPRs, L f16 streamed from L2, dot2 loop, fused f16 epilogue.
// NIT=4: ||A||inf ~ 0.055 -> truncation ~4e-6 rel on X, ~1e-7 on out.

#define NIT 4

typedef _Float16 half2_t __attribute__((ext_vector_type(2)));

// ws f32-offset layout
#define WS_BUT 0                        // 262144 f32: (B@U^T)^T [m][n]
#define WS_LH  262144                   // 32768 u32: L f16 pairs, row n = 32 u32
#define WS_RH  (WS_LH + 32768)          // 32768 u32: R f16 row-pairs [512][64]
#define WS_CH  (WS_RH + 32768)          // 131072 u32: C f16 pairs, row q = 512 u32
#define WS_DH  (WS_CH + 131072)         // 65536 u32: D f16 pairs, row q = 256 u32
#define WS_S   (WS_DH + 65536)          // 1 f32: proj scale s

__device__ __forceinline__ unsigned pk2h(float x, float y) {
  half2_t h;
  h.x = (_Float16)x;
  h.y = (_Float16)y;
  return __builtin_bit_cast(unsigned, h);
}

__device__ __forceinline__ unsigned short f2h(float x) {
  _Float16 h = (_Float16)x;
  return __builtin_bit_cast(unsigned short, h);
}

__device__ __forceinline__ float dot2(unsigned a, unsigned b, float acc) {
#if __has_builtin(__builtin_amdgcn_fdot2)
  return __builtin_amdgcn_fdot2(__builtin_bit_cast(half2_t, a),
                                __builtin_bit_cast(half2_t, b), acc, false);
#else
  half2_t ha = __builtin_bit_cast(half2_t, a);
  half2_t hb = __builtin_bit_cast(half2_t, b);
  acc = fmaf((float)ha.x, (float)hb.x, acc);
  acc = fmaf((float)ha.y, (float)hb.y, acc);
  return acc;
#endif
}

// ---- K1: BUt GEMM + f16 packing + norms, one dispatch, no atomics --------
__global__ __launch_bounds__(256) void k_prep(const float* __restrict__ L,
                                              const float* __restrict__ R,
                                              const float* __restrict__ B,
                                              const float* __restrict__ U,
                                              const float* __restrict__ C,
                                              const float* __restrict__ D,
                                              float* __restrict__ ws) {
  __shared__ __align__(16) float Us[1024], Bs[1024];
  int t = threadIdx.x, b = blockIdx.x;
  if (b < 256) {                        // BUt[m][n] = sum_p B[n][p] U[m][p]
    int n0 = (b & 31) * 32, m0 = (b >> 5) * 32;
    int ti = t & 15, tj = t >> 4;
    int lr = t >> 3, lc = t & 7;
    float4* Us4 = (float4*)Us;
    float4* Bs4 = (float4*)Bs;
    const float4* U4 = (const float4*)U;
    const float4* B4 = (const float4*)B;
    float acc00 = 0, acc01 = 0, acc10 = 0, acc11 = 0;
    for (int kc = 0; kc < 16; ++kc) {
      __syncthreads();
      Us4[lr * 8 + (lc ^ (lr & 7))] = U4[(m0 + lr) * 128 + kc * 8 + lc];
      Bs4[lr * 8 + (lc ^ (lr & 7))] = B4[(n0 + lr) * 128 + kc * 8 + lc];
      __syncthreads();
#pragma unroll
      for (int k4 = 0; k4 < 8; ++k4) {
        float4 u0 = Us4[tj * 8 + (k4 ^ (tj & 7))];
        float4 u1 = Us4[(tj + 16) * 8 + (k4 ^ (tj & 7))];
        float4 b0 = Bs4[ti * 8 + (k4 ^ (ti & 7))];
        float4 b1 = Bs4[(ti + 16) * 8 + (k4 ^ (ti & 7))];
        acc00 += u0.x * b0.x + u0.y * b0.y + u0.z * b0.z + u0.w * b0.w;
        acc01 += u0.x * b1.x + u0.y * b1.y + u0.z * b1.z + u0.w * b1.w;
        acc10 += u1.x * b0.x + u1.y * b0.y + u1.z * b0.z + u1.w * b0.w;
        acc11 += u1.x * b1.x + u1.y * b1.y + u1.z * b1.z + u1.w * b1.w;
      }
    }
    float* BUt = ws + WS_BUT;
    BUt[(m0 + tj) * 1024 + n0 + ti] = acc00;
    BUt[(m0 + tj) * 1024 + n0 + ti + 16] = acc01;
    BUt[(m0 + tj + 16) * 1024 + n0 + ti] = acc10;
    BUt[(m0 + tj + 16) * 1024 + n0 + ti + 16] = acc11;
  } else if (b < 264) {                 // pack L -> f16 pairs (identity layout)
    int idx = (b - 256) * 256 + t;
    const float4* L4 = (const float4*)L;
    uint2* Lh2 = (uint2*)(ws + WS_LH);
#pragma unroll
    for (int h = 0; h < 8; ++h) {
      int f = h * 2048 + idx;           // uint2 slot = n*16 + k4
      float4 v = L4[f];
      uint2 o;
      o.x = pk2h(v.x, v.y);
      o.y = pk2h(v.z, v.w);
      Lh2[f] = o;
    }
  } else if (b < 272) {                 // pack R: Rh[rp*64+k]=(R[2rp][k],R[2rp+1][k])
    int idx = (b - 264) * 256 + t;
    unsigned* Rh = (unsigned*)(ws + WS_RH);
#pragma unroll
    for (int h = 0; h < 16; ++h) {
      int u = h * 2048 + idx;
      int k = u & 63, rp = u >> 6;
      Rh[u] = pk2h(R[rp * 128 + k], R[rp * 128 + 64 + k]);
    }
  } else if (b < 280) {                 // pack C -> f16 pairs (flat)
    int idx = (b - 272) * 256 + t;
    const float2* C2 = (const float2*)C;
    unsigned* Ch = (unsigned*)(ws + WS_CH);
#pragma unroll
    for (int h = 0; h < 64; ++h) {
      int u = h * 2048 + idx;
      float2 v = C2[u];
      Ch[u] = pk2h(v.x, v.y);
    }
  } else if (b < 284) {                 // pack D -> f16 pairs (flat)
    int idx = (b - 280) * 256 + t;
    const float2* D2 = (const float2*)D;
    unsigned* Dh = (unsigned*)(ws + WS_DH);
#pragma unroll
    for (int h = 0; h < 64; ++h) {
      int u = h * 1024 + idx;
      float2 v = D2[u];
      Dh[u] = pk2h(v.x, v.y);
    }
  } else {                              // norms -> s (f32-exact, plain store)
    int lane = t & 63;
    const float4* L4 = (const float4*)L;
    float mx = 0.f;
#pragma unroll 1
    for (int j = 0; j < 4; ++j) {       // rows j*256+t
      int row = j * 256 + t;
      float rs = 0.f;
#pragma unroll
      for (int q = 0; q < 16; ++q) {
        float4 v = L4[row * 16 + q];
        rs += fabsf(v.x) + fabsf(v.y) + fabsf(v.z) + fabsf(v.w);
      }
      mx = fmaxf(mx, rs);
    }
#pragma unroll
    for (int m = 32; m; m >>= 1) mx = fmaxf(mx, __shfl_xor(mx, m));
    if (lane == 0) Bs[t >> 6] = mx;
    int k = t & 63, g = t >> 6;         // ||R^T||inf col sums
    float cs = 0.f;
#pragma unroll 1
    for (int r = 0; r < 256; ++r) cs += fabsf(R[(g * 256 + r) * 64 + k]);
    Us[g * 64 + k] = cs;
    __syncthreads();
    if (t < 64) {
      float col = Us[t] + Us[64 + t] + Us[128 + t] + Us[192 + t];
#pragma unroll
      for (int m = 32; m; m >>= 1) col = fmaxf(col, __shfl_xor(col, m));
      if (t == 0) {
        float nL = fmaxf(fmaxf(Bs[0], Bs[1]), fmaxf(Bs[2], Bs[3]));
        ws[WS_S] = (nL > 0.97f ? 0.97f / nL : 1.f) *
                   (col > 0.97f ? 0.97f / col : 1.f);
      }
    }
  }
}

// ---- K2: fixed-point loop + fused f16 epilogue. 256 blocks x 1024 thr. ---
__global__ __launch_bounds__(1024, 4) void k_main(const float* __restrict__ U,
                                                  float* __restrict__ ws,
                                                  float* __restrict__ out) {
  __shared__ __align__(16) unsigned short x_h[1024];
  __shared__ __align__(16) unsigned short u_h[512];
  __shared__ __align__(16) float tpart[16][64];
  __shared__ __align__(16) unsigned t_u[32];
  int tid = threadIdx.x, w = tid >> 6, lane = tid & 63;
  int c = blockIdx.x;
  // R column `lane`, rows [w*64, w*64+64) as f16 pairs: 32 VGPR
  const unsigned* Rh = (const unsigned*)(ws + WS_RH);
  unsigned Rr[32];
#pragma unroll
  for (int r2 = 0; r2 < 32; ++r2) Rr[r2] = Rh[(w * 32 + r2) * 64 + lane];
  float bu = ws[WS_BUT + c * 1024 + tid];
  float s = ws[WS_S];
  if (tid < 256)                        // U[c,:] -> f16 pairs in LDS
    ((unsigned*)u_h)[tid] = pk2h(U[c * 512 + 2 * tid], U[c * 512 + 2 * tid + 1]);
  float a = fmaxf(bu, 0.f);             // X1 = relu(BU)
  x_h[tid] = f2h(a);
  __syncthreads();
  const uint4* Lh4 = (const uint4*)(ws + WS_LH);   // row n = 8 uint4 (64 f16)
  const uint4* xh4 = (const uint4*)x_h;
  const uint4* t4 = (const uint4*)t_u;
  for (int it = 0; it < NIT - 1; ++it) {
    // phase 2: tpart[w][lane] = sum_{n in wave rows} R[n][lane]*x[n] (wave-local)
    float t0 = 0.f, t1 = 0.f, t2 = 0.f, t3 = 0.f;
#pragma unroll
    for (int r = 0; r < 8; ++r) {
      uint4 xv = xh4[w * 8 + r];
      t0 = dot2(Rr[4 * r + 0], xv.x, t0);
      t1 = dot2(Rr[4 * r + 1], xv.y, t1);
      t2 = dot2(Rr[4 * r + 2], xv.z, t2);
      t3 = dot2(Rr[4 * r + 3], xv.w, t3);
    }
    tpart[w][lane] = (t0 + t1) + (t2 + t3);
    __syncthreads();
    if (tid < 32) {                     // t = s*(R^T x) as f16 pairs
      float sa = 0.f, sb = 0.f;
#pragma unroll
      for (int g = 0; g < 16; ++g) {
        sa += tpart[g][2 * tid];
        sb += tpart[g][2 * tid + 1];
      }
      t_u[tid] = pk2h(s * sa, s * sb);
    }
    __syncthreads();
    // phase 1: x[tid] = relu(bu + L[tid,:].t)  -- L f16 streamed from L2
    float b0 = 0.f, b1 = 0.f, b2 = 0.f, b3 = 0.f;
#pragma unroll
    for (int ss = 0; ss < 8; ++ss) {
      uint4 lv = Lh4[tid * 8 + ss];
      uint4 tv = t4[ss];
      b0 = dot2(lv.x, tv.x, b0);
      b1 = dot2(lv.y, tv.y, b1);
      b2 = dot2(lv.z, tv.z, b2);
      b3 = dot2(lv.w, tv.w, b3);
    }
    a = fmaxf(bu + ((b0 + b1) + (b2 + b3)), 0.f);
    x_h[tid] = f2h(a);                  // wave-local rows: no barrier needed
  }
  __syncthreads();                      // all waves' x needed below
  // ---- fused epilogue: out[c][q] = C[q,:].x + D[q,:].U[c,:]  (all f16) ----
  const uint4* Ch4 = (const uint4*)(ws + WS_CH);   // row q = 128 uint4
  const uint4* Dh4 = (const uint4*)(ws + WS_DH);   // row q = 64 uint4
  const uint4* uh4 = (const uint4*)u_h;            // 64 uint4
#pragma unroll 1
  for (int i = 0; i < 16; ++i) {
    int q = w * 16 + i;
    float acc = 0.f;
#pragma unroll
    for (int seg = 0; seg < 2; ++seg) {
      uint4 cv = Ch4[q * 128 + seg * 64 + lane];
      uint4 xv = xh4[seg * 64 + lane];
      acc = dot2(cv.x, xv.x, acc);
      acc = dot2(cv.y, xv.y, acc);
      acc = dot2(cv.z, xv.z, acc);
      acc = dot2(cv.w, xv.w, acc);
    }
    {
      uint4 dv = Dh4[q * 64 + lane];
      uint4 uv = uh4[lane];
      acc = dot2(dv.x, uv.x, acc);
      acc = dot2(dv.y, uv.y, acc);
      acc = dot2(dv.z, uv.z, acc);
      acc = dot2(dv.w, uv.w, acc);
    }
#pragma unroll
    for (int m = 32; m; m >>= 1) acc += __shfl_xor(acc, m);
    if (lane == 0) out[c * 256 + q] = acc;
  }
}

extern "C" void kernel_launch(void* const* d_in, const int* in_sizes, int n_in,
                              void* d_out, int out_size, void* d_ws, size_t ws_size,
                              hipStream_t stream) {
  const float* U = (const float*)d_in[0];
  const float* L = (const float*)d_in[1];
  const float* R = (const float*)d_in[2];
  const float* B = (const float*)d_in[3];
  const float* C = (const float*)d_in[4];
  const float* D = (const float*)d_in[5];
  float* ws = (float*)d_ws;
  float* out = (float*)d_out;
  hipLaunchKernelGGL(k_prep, dim3(285), dim3(256), 0, stream, L, R, B, U, C, D, ws);
  hipLaunchKernelGGL(k_main, dim3(256), dim3(1024), 0, stream, U, ws, out);
}

// Round 12
// 105.298 us; speedup vs baseline: 1.4510x; 1.4510x over previous
//
#include <hip/hip_runtime.h>

// ImplicitModelLoRA: X = relu(s*L*(R^T X) + B U^T) iterated; out = (C X + D U^T)^T
// Round-11 (resubmit; bench lost to GPU acquisition timeout):
// fix r10's serial-tail norm block (72us one-block tail). Norms move
// into k_main (R from regs, L from one f16 sweep). k_main now owns 2 columns
// per block (128 blocks): Rr/L-row loads and the epilogue C/D sweep amortize
// over both columns (epilogue L2 traffic halved to 96 MB).
// NIT=4: ||A||inf ~ 0.055 -> truncation ~1e-6 rel; absmax 4.88e-4 = f16 C ulp.

#define NIT 4

typedef _Float16 half2_t __attribute__((ext_vector_type(2)));

// ws f32-offset layout
#define WS_BUT 0                        // 262144 f32: (B@U^T)^T [m][n]
#define WS_LH  262144                   // 32768 u32: L f16 pairs, row n = 32 u32
#define WS_RH  (WS_LH + 32768)          // 32768 u32: R f16 row-pairs [512][64]
#define WS_CH  (WS_RH + 32768)          // 131072 u32: C f16 pairs, row q = 512 u32
#define WS_DH  (WS_CH + 131072)         // 65536 u32: D f16 pairs, row q = 256 u32

__device__ __forceinline__ unsigned pk2h(float x, float y) {
  half2_t h;
  h.x = (_Float16)x;
  h.y = (_Float16)y;
  return __builtin_bit_cast(unsigned, h);
}

__device__ __forceinline__ unsigned short f2h(float x) {
  _Float16 h = (_Float16)x;
  return __builtin_bit_cast(unsigned short, h);
}

__device__ __forceinline__ float dot2(unsigned a, unsigned b, float acc) {
#if __has_builtin(__builtin_amdgcn_fdot2)
  return __builtin_amdgcn_fdot2(__builtin_bit_cast(half2_t, a),
                                __builtin_bit_cast(half2_t, b), acc, false);
#else
  half2_t ha = __builtin_bit_cast(half2_t, a);
  half2_t hb = __builtin_bit_cast(half2_t, b);
  acc = fmaf((float)ha.x, (float)hb.x, acc);
  acc = fmaf((float)ha.y, (float)hb.y, acc);
  return acc;
#endif
}

__device__ __forceinline__ float abssum2(unsigned u) {
  half2_t h = __builtin_bit_cast(half2_t, u & 0x7FFF7FFFu);
  return (float)h.x + (float)h.y;
}

// ---- K1: BUt GEMM (blocks 0..255) + f16 packing (256..283). No norms. ----
__global__ __launch_bounds__(256) void k_prep(const float* __restrict__ L,
                                              const float* __restrict__ R,
                                              const float* __restrict__ B,
                                              const float* __restrict__ U,
                                              const float* __restrict__ C,
                                              const float* __restrict__ D,
                                              float* __restrict__ ws) {
  __shared__ __align__(16) float Us[1024], Bs[1024];
  int t = threadIdx.x, b = blockIdx.x;
  if (b < 256) {                        // BUt[m][n] = sum_p B[n][p] U[m][p]
    int n0 = (b & 31) * 32, m0 = (b >> 5) * 32;
    int ti = t & 15, tj = t >> 4;
    int lr = t >> 3, lc = t & 7;
    float4* Us4 = (float4*)Us;
    float4* Bs4 = (float4*)Bs;
    const float4* U4 = (const float4*)U;
    const float4* B4 = (const float4*)B;
    float acc00 = 0, acc01 = 0, acc10 = 0, acc11 = 0;
    for (int kc = 0; kc < 16; ++kc) {
      __syncthreads();
      Us4[lr * 8 + (lc ^ (lr & 7))] = U4[(m0 + lr) * 128 + kc * 8 + lc];
      Bs4[lr * 8 + (lc ^ (lr & 7))] = B4[(n0 + lr) * 128 + kc * 8 + lc];
      __syncthreads();
#pragma unroll
      for (int k4 = 0; k4 < 8; ++k4) {
        float4 u0 = Us4[tj * 8 + (k4 ^ (tj & 7))];
        float4 u1 = Us4[(tj + 16) * 8 + (k4 ^ (tj & 7))];
        float4 b0 = Bs4[ti * 8 + (k4 ^ (ti & 7))];
        float4 b1 = Bs4[(ti + 16) * 8 + (k4 ^ (ti & 7))];
        acc00 += u0.x * b0.x + u0.y * b0.y + u0.z * b0.z + u0.w * b0.w;
        acc01 += u0.x * b1.x + u0.y * b1.y + u0.z * b1.z + u0.w * b1.w;
        acc10 += u1.x * b0.x + u1.y * b0.y + u1.z * b0.z + u1.w * b0.w;
        acc11 += u1.x * b1.x + u1.y * b1.y + u1.z * b1.z + u1.w * b1.w;
      }
    }
    float* BUt = ws + WS_BUT;
    BUt[(m0 + tj) * 1024 + n0 + ti] = acc00;
    BUt[(m0 + tj) * 1024 + n0 + ti + 16] = acc01;
    BUt[(m0 + tj + 16) * 1024 + n0 + ti] = acc10;
    BUt[(m0 + tj + 16) * 1024 + n0 + ti + 16] = acc11;
  } else if (b < 264) {                 // pack L -> f16 pairs (identity layout)
    int idx = (b - 256) * 256 + t;
    const float4* L4 = (const float4*)L;
    uint2* Lh2 = (uint2*)(ws + WS_LH);
#pragma unroll
    for (int h = 0; h < 8; ++h) {
      int f = h * 2048 + idx;           // uint2 slot = n*16 + k4
      float4 v = L4[f];
      uint2 o;
      o.x = pk2h(v.x, v.y);
      o.y = pk2h(v.z, v.w);
      Lh2[f] = o;
    }
  } else if (b < 272) {                 // pack R: Rh[rp*64+k]=(R[2rp][k],R[2rp+1][k])
    int idx = (b - 264) * 256 + t;
    unsigned* Rh = (unsigned*)(ws + WS_RH);
#pragma unroll
    for (int h = 0; h < 16; ++h) {
      int u = h * 2048 + idx;
      int k = u & 63, rp = u >> 6;
      Rh[u] = pk2h(R[rp * 128 + k], R[rp * 128 + 64 + k]);
    }
  } else if (b < 280) {                 // pack C -> f16 pairs (flat)
    int idx = (b - 272) * 256 + t;
    const float2* C2 = (const float2*)C;
    unsigned* Ch = (unsigned*)(ws + WS_CH);
#pragma unroll
    for (int h = 0; h < 64; ++h) {
      int u = h * 2048 + idx;
      float2 v = C2[u];
      Ch[u] = pk2h(v.x, v.y);
    }
  } else {                              // pack D -> f16 pairs (flat)
    int idx = (b - 280) * 256 + t;
    const float2* D2 = (const float2*)D;
    unsigned* Dh = (unsigned*)(ws + WS_DH);
#pragma unroll
    for (int h = 0; h < 64; ++h) {
      int u = h * 1024 + idx;
      float2 v = D2[u];
      Dh[u] = pk2h(v.x, v.y);
    }
  }
}

// ---- K2: loop + epilogue, 2 columns per block. 128 blocks x 1024 thr. ----
__global__ __launch_bounds__(1024, 4) void k_main(const float* __restrict__ U,
                                                  float* __restrict__ ws,
                                                  float* __restrict__ out) {
  __shared__ __align__(16) unsigned short x_h[2][1024];
  __shared__ __align__(16) unsigned short u_h[2][512];
  __shared__ __align__(16) float tpart[2][16][64];
  __shared__ __align__(16) unsigned t_u[2][32];
  __shared__ float redL[16];
  __shared__ float s_sh;
  int tid = threadIdx.x, w = tid >> 6, lane = tid & 63;
  int c0 = blockIdx.x * 2;
  // R column `lane`, rows [w*64, w*64+64) as f16 pairs: 32 VGPR (shared by cols)
  const unsigned* Rh = (const unsigned*)(ws + WS_RH);
  unsigned Rr[32];
#pragma unroll
  for (int r2 = 0; r2 < 32; ++r2) Rr[r2] = Rh[(w * 32 + r2) * 64 + lane];
  // ||R^T||inf partial from registers
  float cs = 0.f;
#pragma unroll
  for (int r2 = 0; r2 < 32; ++r2) cs += abssum2(Rr[r2]);
  tpart[0][w][lane] = cs;
  // ||L||inf pre-pass from packed f16 L row tid (L2-warm from k_prep)
  const uint4* Lh4 = (const uint4*)(ws + WS_LH);   // row n = 8 uint4 (64 f16)
  {
    float rs = 0.f;
#pragma unroll
    for (int j = 0; j < 8; ++j) {
      uint4 lv = Lh4[tid * 8 + j];
      rs += abssum2(lv.x) + abssum2(lv.y) + abssum2(lv.z) + abssum2(lv.w);
    }
#pragma unroll
    for (int m = 32; m; m >>= 1) rs = fmaxf(rs, __shfl_xor(rs, m));
    if (lane == 0) redL[w] = rs;
  }
  float bu0 = ws[WS_BUT + c0 * 1024 + tid];
  float bu1 = ws[WS_BUT + (c0 + 1) * 1024 + tid];
  if (tid < 512) {                      // U rows c0,c0+1 -> f16 pairs in LDS
    int cc = tid >> 8, i = tid & 255;
    ((unsigned*)u_h)[tid] =
        pk2h(U[(c0 + cc) * 512 + 2 * i], U[(c0 + cc) * 512 + 2 * i + 1]);
  }
  float a0 = fmaxf(bu0, 0.f), a1 = fmaxf(bu1, 0.f);  // X1 = relu(BU)
  x_h[0][tid] = f2h(a0);
  x_h[1][tid] = f2h(a1);
  __syncthreads();
  if (tid < 64) {                       // combine norms -> s
    float col = 0.f;
#pragma unroll
    for (int g = 0; g < 16; ++g) col += tpart[0][g][tid];
#pragma unroll
    for (int m = 32; m; m >>= 1) col = fmaxf(col, __shfl_xor(col, m));
    if (tid == 0) {
      float nL = 0.f;
#pragma unroll
      for (int g = 0; g < 16; ++g) nL = fmaxf(nL, redL[g]);
      s_sh = (nL > 0.97f ? 0.97f / nL : 1.f) * (col > 0.97f ? 0.97f / col : 1.f);
    }
  }
  __syncthreads();
  float s = s_sh;
  const uint4* xh40 = (const uint4*)x_h[0];
  const uint4* xh41 = (const uint4*)x_h[1];
  const uint4* t40 = (const uint4*)t_u[0];
  const uint4* t41 = (const uint4*)t_u[1];
  for (int it = 0; it < NIT - 1; ++it) {
    // phase 2: per-wave partial of R^T x for both columns (wave-local x rows)
    float t0 = 0.f, t1 = 0.f, t2 = 0.f, t3 = 0.f;
    float v0 = 0.f, v1 = 0.f, v2 = 0.f, v3 = 0.f;
#pragma unroll
    for (int r = 0; r < 8; ++r) {
      uint4 xa = xh40[w * 8 + r];
      uint4 xb = xh41[w * 8 + r];
      t0 = dot2(Rr[4 * r + 0], xa.x, t0);
      t1 = dot2(Rr[4 * r + 1], xa.y, t1);
      t2 = dot2(Rr[4 * r + 2], xa.z, t2);
      t3 = dot2(Rr[4 * r + 3], xa.w, t3);
      v0 = dot2(Rr[4 * r + 0], xb.x, v0);
      v1 = dot2(Rr[4 * r + 1], xb.y, v1);
      v2 = dot2(Rr[4 * r + 2], xb.z, v2);
      v3 = dot2(Rr[4 * r + 3], xb.w, v3);
    }
    tpart[0][w][lane] = (t0 + t1) + (t2 + t3);
    tpart[1][w][lane] = (v0 + v1) + (v2 + v3);
    __syncthreads();
    if (tid < 64) {                     // t = s*(R^T x) as f16 pairs, both cols
      int cc = tid >> 5, i = tid & 31;
      float sa = 0.f, sb = 0.f;
#pragma unroll
      for (int g = 0; g < 16; ++g) {
        sa += tpart[cc][g][2 * i];
        sb += tpart[cc][g][2 * i + 1];
      }
      t_u[cc][i] = pk2h(s * sa, s * sb);
    }
    __syncthreads();
    // phase 1: x[tid] = relu(bu + L[tid,:].t)  -- L f16 from L2, reused 2x
    float b00 = 0.f, b01 = 0.f, b02 = 0.f, b03 = 0.f;
    float b10 = 0.f, b11 = 0.f, b12 = 0.f, b13 = 0.f;
#pragma unroll
    for (int ss = 0; ss < 8; ++ss) {
      uint4 lv = Lh4[tid * 8 + ss];
      uint4 ta = t40[ss];
      uint4 tb = t41[ss];
      b00 = dot2(lv.x, ta.x, b00);
      b01 = dot2(lv.y, ta.y, b01);
      b02 = dot2(lv.z, ta.z, b02);
      b03 = dot2(lv.w, ta.w, b03);
      b10 = dot2(lv.x, tb.x, b10);
      b11 = dot2(lv.y, tb.y, b11);
      b12 = dot2(lv.z, tb.z, b12);
      b13 = dot2(lv.w, tb.w, b13);
    }
    a0 = fmaxf(bu0 + ((b00 + b01) + (b02 + b03)), 0.f);
    a1 = fmaxf(bu1 + ((b10 + b11) + (b12 + b13)), 0.f);
    x_h[0][tid] = f2h(a0);              // wave-local rows: no barrier needed
    x_h[1][tid] = f2h(a1);
  }
  __syncthreads();                      // all waves' x needed below
  // ---- fused epilogue: out[c][q] = C[q,:].x + D[q,:].U[c,:], both cols ----
  const uint4* Ch4 = (const uint4*)(ws + WS_CH);   // row q = 128 uint4
  const uint4* Dh4 = (const uint4*)(ws + WS_DH);   // row q = 64 uint4
  const uint4* uh40 = (const uint4*)u_h[0];
  const uint4* uh41 = (const uint4*)u_h[1];
#pragma unroll 1
  for (int i = 0; i < 16; ++i) {
    int q = w * 16 + i;
    float acc0 = 0.f, acc1 = 0.f;
#pragma unroll
    for (int seg = 0; seg < 2; ++seg) {
      uint4 cv = Ch4[q * 128 + seg * 64 + lane];
      uint4 xa = xh40[seg * 64 + lane];
      uint4 xb = xh41[seg * 64 + lane];
      acc0 = dot2(cv.x, xa.x, acc0);
      acc0 = dot2(cv.y, xa.y, acc0);
      acc0 = dot2(cv.z, xa.z, acc0);
      acc0 = dot2(cv.w, xa.w, acc0);
      acc1 = dot2(cv.x, xb.x, acc1);
      acc1 = dot2(cv.y, xb.y, acc1);
      acc1 = dot2(cv.z, xb.z, acc1);
      acc1 = dot2(cv.w, xb.w, acc1);
    }
    {
      uint4 dv = Dh4[q * 64 + lane];
      uint4 ua = uh40[lane];
      uint4 ub = uh41[lane];
      acc0 = dot2(dv.x, ua.x, acc0);
      acc0 = dot2(dv.y, ua.y, acc0);
      acc0 = dot2(dv.z, ua.z, acc0);
      acc0 = dot2(dv.w, ua.w, acc0);
      acc1 = dot2(dv.x, ub.x, acc1);
      acc1 = dot2(dv.y, ub.y, acc1);
      acc1 = dot2(dv.z, ub.z, acc1);
      acc1 = dot2(dv.w, ub.w, acc1);
    }
#pragma unroll
    for (int m = 32; m; m >>= 1) {
      acc0 += __shfl_xor(acc0, m);
      acc1 += __shfl_xor(acc1, m);
    }
    if (lane == 0) {
      out[c0 * 256 + q] = acc0;
      out[(c0 + 1) * 256 + q] = acc1;
    }
  }
}

extern "C" void kernel_launch(void* const* d_in, const int* in_sizes, int n_in,
                              void* d_out, int out_size, void* d_ws, size_t ws_size,
                              hipStream_t stream) {
  const float* U = (const float*)d_in[0];
  const float* L = (const float*)d_in[1];
  const float* R = (const float*)d_in[2];
  const float* B = (const float*)d_in[3];
  const float* C = (const float*)d_in[4];
  const float* D = (const float*)d_in[5];
  float* ws = (float*)d_ws;
  float* out = (float*)d_out;
  hipLaunchKernelGGL(k_prep, dim3(284), dim3(256), 0, stream, L, R, B, U, C, D, ws);
  hipLaunchKernelGGL(k_main, dim3(128), dim3(1024), 0, stream, U, ws, out);
}